// Round 10
// baseline (526.124 us; speedup 1.0000x reference)
//
#include <hip/hip_runtime.h>

constexpr int HH   = 4;    // heads
constexpr int DINC = 128;  // input feature dim
constexpr int OUTC = 128;  // output feature dim (H*D)
constexpr int NCMB = 272;  // combined B cols: 128 Ws | 128 Wd | 4 vs | 4 vd | 8 pad
constexpr int SCAN_B = 64;

typedef __attribute__((ext_vector_type(4))) float f32x4;
typedef __attribute__((ext_vector_type(2))) float f32x2;
typedef __attribute__((ext_vector_type(8))) short bf16x8;
typedef __attribute__((ext_vector_type(2))) unsigned int u32x2;

__device__ __forceinline__ float leaky(float x){ return x >= 0.f ? x : 0.2f*x; }
__device__ __forceinline__ unsigned short f2bf(float f){ unsigned u=__float_as_uint(f); return (unsigned short)((u + 0x7FFFu + ((u>>16)&1u))>>16); }
__device__ __forceinline__ float bf2f(unsigned s){ return __uint_as_float(s<<16); }

// ---------------- K0: prep — element-parallel (+ deg zeroing) ----------------
__global__ __launch_bounds__(256) void prep_kernel(
    const float* __restrict__ Ws, const float* __restrict__ Wd, const float* __restrict__ We,
    const float* __restrict__ as_, const float* __restrict__ ad_, const float* __restrict__ ae_,
    unsigned short* __restrict__ wcmb, unsigned short* __restrict__ webft,
    unsigned short* __restrict__ veb, int* __restrict__ deg, int N)
{
  int tid = blockIdx.x*256 + threadIdx.x;
  int stride = gridDim.x*256;
  for (int idx = tid; idx < NCMB*DINC; idx += stride) {
    int j = idx >> 7, k = idx & 127;
    float w;
    if      (j < 128) w = Ws[j*DINC + k];
    else if (j < 256) w = Wd[(j-128)*DINC + k];
    else if (j < 260) { int h=j-256; float s=0.f; for(int d=0;d<32;++d) s += as_[h*32+d]*Ws[(h*32+d)*DINC+k]; w=s; }
    else if (j < 264) { int h=j-260; float s=0.f; for(int d=0;d<32;++d) s += ad_[h*32+d]*Wd[(h*32+d)*DINC+k]; w=s; }
    else w = 0.f;
    wcmb[idx] = f2bf(w);
  }
  for (int idx = tid; idx < 16*DINC; idx += stride) {   // veb[16][128]: 4 real head rows
    int h = idx >> 7, k = idx & 127;
    float w = 0.f;
    if (h < HH) { float s=0.f; for(int d=0;d<32;++d) s += ae_[h*32+d]*We[(h*32+d)*DINC+k]; w=s; }
    veb[idx] = f2bf(w);
  }
  for (int idx = tid; idx < DINC*OUTC; idx += stride)   // webft[j][k] = We row-major bf16
    webft[idx] = f2bf(We[idx]);
  for (int idx = tid; idx < N; idx += stride) deg[idx] = 0;
}

// ---------------- K1: MFMA node GEMM C[32,272] = X @ [Ws|Wd|vs|vd]^T + fused histogram ----------------
__global__ __launch_bounds__(256) void node_mfma(
    const float* __restrict__ X, const unsigned short* __restrict__ wcmb,
    const int* __restrict__ dst, int* __restrict__ deg,
    unsigned short* __restrict__ hsrcbf, unsigned short* __restrict__ hdstbf,
    float* __restrict__ esrc, float* __restrict__ edst, int N, int E)
{
  int t = threadIdx.x;
  for (long e = (long)blockIdx.x*256 + t; e < E; e += (long)gridDim.x*256)
    atomicAdd(deg + dst[e], 1);

  int lane = t & 63, wv = t >> 6;
  int r16 = lane & 15, g = lane >> 4;
  int n0 = blockIdx.x * 32;
  int ntS = (wv*17) >> 2, ntE = ((wv+1)*17) >> 2;

  #pragma unroll
  for (int mt = 0; mt < 2; ++mt) {
    int arow = n0 + mt*16 + r16; if (arow >= N) arow = N-1;
    bf16x8 a[4];
    #pragma unroll
    for (int kc = 0; kc < 4; ++kc) {
      const float* ap = X + (long)arow*DINC + kc*32 + g*8;
      f32x4 x0 = *(const f32x4*)ap;
      f32x4 x1 = *(const f32x4*)(ap + 4);
      bf16x8 af;
      af[0]=f2bf(x0[0]); af[1]=f2bf(x0[1]); af[2]=f2bf(x0[2]); af[3]=f2bf(x0[3]);
      af[4]=f2bf(x1[0]); af[5]=f2bf(x1[1]); af[6]=f2bf(x1[2]); af[7]=f2bf(x1[3]);
      a[kc] = af;
    }
    for (int nt = ntS; nt < ntE; ++nt) {
      f32x4 acc = (f32x4){0,0,0,0};
      #pragma unroll
      for (int kc = 0; kc < 4; ++kc) {
        bf16x8 bf = *(const bf16x8*)(wcmb + (nt*16 + r16)*DINC + kc*32 + g*8);
        acc = __builtin_amdgcn_mfma_f32_16x16x32_bf16(a[kc], bf, acc, 0, 0, 0);
      }
      int j = nt*16 + r16;   // D: col = lane&15, row = g*4 + r
      #pragma unroll
      for (int r = 0; r < 4; ++r) {
        int n = n0 + mt*16 + g*4 + r;
        if (n >= N) continue;
        float v = acc[r];
        if      (j < 128) hsrcbf[(long)n*OUTC + j] = f2bf(v);
        else if (j < 256) hdstbf[(long)n*OUTC + (j-128)] = f2bf(v);
        else if (j < 260) esrc[(long)n*HH + (j-256)] = v;
        else if (j < 264) edst[(long)n*HH + (j-260)] = v;
      }
    }
  }
}

// ---------------- scan: 3-phase parallel exclusive scan of deg ----------------
__global__ __launch_bounds__(256) void scan1(const int* __restrict__ deg, int* __restrict__ bsum, int N)
{
  __shared__ int sh[256];
  int t = threadIdx.x, blk = blockIdx.x;
  int R = (N + SCAN_B*256 - 1) / (SCAN_B*256);
  int base = (blk*256 + t)*R;
  int s = 0;
  for (int i = 0; i < R; ++i) { int idx = base + i; if (idx < N) s += deg[idx]; }
  sh[t] = s; __syncthreads();
  for (int d = 128; d > 0; d >>= 1) { if (t < d) sh[t] += sh[t+d]; __syncthreads(); }
  if (t == 0) bsum[blk] = sh[0];
}

__global__ __launch_bounds__(64) void scan2(const int* __restrict__ bsum, int* __restrict__ bpre,
                                            int* __restrict__ off, int N)
{
  if (threadIdx.x == 0) {
    int r = 0;
    for (int b = 0; b < SCAN_B; ++b) { bpre[b] = r; r += bsum[b]; }
    off[N] = r;
  }
}

__global__ __launch_bounds__(256) void scan3(const int* __restrict__ deg, const int* __restrict__ bpre,
                                             int* __restrict__ off, int* __restrict__ cursor, int N)
{
  __shared__ int sh[256];
  int t = threadIdx.x, blk = blockIdx.x;
  int R = (N + SCAN_B*256 - 1) / (SCAN_B*256);
  int base = (blk*256 + t)*R;
  int s = 0;
  for (int i = 0; i < R; ++i) { int idx = base + i; if (idx < N) s += deg[idx]; }
  sh[t] = s; __syncthreads();
  for (int d = 1; d < 256; d <<= 1) {
    int v = (t >= d) ? sh[t-d] : 0;
    __syncthreads();
    sh[t] += v;
    __syncthreads();
  }
  int r = bpre[blk] + sh[t] - s;
  for (int i = 0; i < R; ++i) {
    int idx = base + i;
    if (idx < N) { off[idx] = r; cursor[idx] = r; r += deg[idx]; }
  }
}

// ---------------- scatter: 8B CSR records {src, eid} ----------------
__global__ __launch_bounds__(256) void scatter_kernel(
    const int* __restrict__ src, const int* __restrict__ dst,
    int* __restrict__ cursor, unsigned long long* __restrict__ csr, int E)
{
  int e = blockIdx.x*256 + threadIdx.x;
  if (e >= E) return;
  int p = atomicAdd(cursor + dst[e], 1);
  csr[p] = ((unsigned long long)(unsigned)src[e] << 32) | (unsigned)e;
}

// ---------------- K4: FUSED aggregation — all accumulation on the MFMA pipe ----------------
// Wave = node. Per 16-edge chunk:
//   logit MFMA (A=Xe frags, B=veb)   -> nu2 lands already in coef-B-frag layout
//   identity-MFMA transposes data frags (A-layout -> D-layout == next A-layout)
//   Y-MFMA (K=32, slots 4-7 zero): Y[feat][head] += data^T @ coef
// Projection Y@We^T is 32 more MFMAs. No block barriers (LDS wave-local).
__global__ __launch_bounds__(256, 2) void aggregate_fused(
    const float* __restrict__ Xe, const unsigned short* __restrict__ veb,
    const unsigned short* __restrict__ hsrcb, const unsigned* __restrict__ hdstbfu,
    const float* __restrict__ esrc, const float* __restrict__ edst,
    const unsigned long long* __restrict__ csr, const int* __restrict__ off,
    const unsigned short* __restrict__ webft, float* __restrict__ out, int N)
{
  __shared__ unsigned short Ybf[4][HH][136];  // bf16 Y (xe path), pre-scaled by 1/s2
  __shared__ float Yh1[4][132];               // diag-head h_neigh, pre-scaled by 1/s1
  __shared__ float OutPl[4][132];             // projected edge-path output

  int t = threadIdx.x, wid = t >> 6, lane = t & 63;
  int r16 = lane & 15, g = lane >> 4;
  int n = blockIdx.x*4 + wid;
  bool valid = (n < N);
  int beg = 0, end = 0;
  if (valid) { beg = off[n]; end = off[n+1]; }
  f32x4 edh4 = valid ? *(const f32x4*)(edst + (long)n*HH) : (f32x4){0,0,0,0};
  float edh = edh4[r16 & 3];

  bf16x8 vebf[4];
  #pragma unroll
  for (int kc = 0; kc < 4; ++kc)
    vebf[kc] = *(const bf16x8*)(veb + r16*DINC + kc*32 + g*8);

  // identity B-frags: B[k][j] = (k==j) / (k==j+16)
  bf16x8 idf0, idf1;
  #pragma unroll
  for (int i = 0; i < 8; ++i) {
    idf0[i] = (g*8 + i == r16)      ? (short)0x3F80 : (short)0;
    idf1[i] = (g*8 + i == r16 + 16) ? (short)0x3F80 : (short)0;
  }

  f32x4 Yx[8], Yh[8];
  #pragma unroll
  for (int i = 0; i < 8; ++i) { Yx[i] = (f32x4){0,0,0,0}; Yh[i] = (f32x4){0,0,0,0}; }
  float s1s = 0.f, s2s = 0.f;

  for (int p0 = beg; p0 < end; p0 += 16) {
    long pr = (long)p0 + r16; if (pr >= end) pr = end - 1;
    unsigned long long pk = csr[pr];
    int s_ = (int)(pk >> 32);
    long eid = (long)(unsigned)pk;

    bf16x8 axe[4], ah[4];
    #pragma unroll
    for (int kc = 0; kc < 4; ++kc) {
      const float* ap = Xe + eid*DINC + kc*32 + g*8;
      f32x4 x0 = *(const f32x4*)ap;
      f32x4 x1 = *(const f32x4*)(ap + 4);
      bf16x8 af;
      af[0]=f2bf(x0[0]); af[1]=f2bf(x0[1]); af[2]=f2bf(x0[2]); af[3]=f2bf(x0[3]);
      af[4]=f2bf(x1[0]); af[5]=f2bf(x1[1]); af[6]=f2bf(x1[2]); af[7]=f2bf(x1[3]);
      axe[kc] = af;
      ah[kc] = *(const bf16x8*)(hsrcb + (long)s_*DINC + kc*32 + g*8);
    }

    // logits: D[edge g*4+r][head r16]
    f32x4 lg = (f32x4){0,0,0,0};
    #pragma unroll
    for (int kc = 0; kc < 4; ++kc)
      lg = __builtin_amdgcn_mfma_f32_16x16x32_bf16(axe[kc], vebf[kc], lg, 0, 0, 0);

    // coef B-frags (k-slot g*8+i = edge g*4+i for i<4; slots 4-7 zero)
    bf16x8 bc1 = (bf16x8){0,0,0,0,0,0,0,0};
    bf16x8 bc2 = (bf16x8){0,0,0,0,0,0,0,0};
    #pragma unroll
    for (int i = 0; i < 4; ++i) {
      int sj = __shfl(s_, g*4 + i, 64);
      float es = esrc[(long)sj*HH + (r16 & 3)];
      bool vs = (p0 + g*4 + i) < end;
      float n1 = vs ? __expf(leaky(es + edh))    : 0.f;
      float n2 = vs ? __expf(leaky(lg[i] + edh)) : 0.f;
      unsigned short b1 = f2bf(n1), b2 = f2bf(n2);
      bc1[i] = (short)b1; bc2[i] = (short)b2;
      s1s += bf2f(b1); s2s += bf2f(b2);
    }

    // transpose (identity MFMA) + Y accumulate
    #pragma unroll
    for (int kc = 0; kc < 4; ++kc) {
      #pragma unroll
      for (int h2 = 0; h2 < 2; ++h2) {
        int tt = kc*2 + h2;
        bf16x8 idv = h2 ? idf1 : idf0;
        f32x4 Dx = __builtin_amdgcn_mfma_f32_16x16x32_bf16(axe[kc], idv, (f32x4){0,0,0,0}, 0, 0, 0);
        bf16x8 a2;
        a2[0]=f2bf(Dx[0]); a2[1]=f2bf(Dx[1]); a2[2]=f2bf(Dx[2]); a2[3]=f2bf(Dx[3]);
        a2[4]=0; a2[5]=0; a2[6]=0; a2[7]=0;
        Yx[tt] = __builtin_amdgcn_mfma_f32_16x16x32_bf16(a2, bc2, Yx[tt], 0, 0, 0);
        f32x4 Dh = __builtin_amdgcn_mfma_f32_16x16x32_bf16(ah[kc], idv, (f32x4){0,0,0,0}, 0, 0, 0);
        bf16x8 a2h;
        a2h[0]=f2bf(Dh[0]); a2h[1]=f2bf(Dh[1]); a2h[2]=f2bf(Dh[2]); a2h[3]=f2bf(Dh[3]);
        a2h[4]=0; a2h[5]=0; a2h[6]=0; a2h[7]=0;
        Yh[tt] = __builtin_amdgcn_mfma_f32_16x16x32_bf16(a2h, bc1, Yh[tt], 0, 0, 0);
      }
    }
  }

  // denominators: reduce partials across g (lane^16, lane^32 keep r16)
  s1s += __shfl_xor(s1s, 16, 64); s1s += __shfl_xor(s1s, 32, 64);
  s2s += __shfl_xor(s2s, 16, 64); s2s += __shfl_xor(s2s, 32, 64);
  float is1 = (s1s != 0.f) ? 1.f/s1s : 0.f;
  float is2 = (s2s != 0.f) ? 1.f/s2s : 0.f;

  // Y (D-layout: lane r16 = head col, rows g*4+r = feats of tile tt) -> LDS
  if (r16 < HH) {
    #pragma unroll
    for (int tt = 0; tt < 8; ++tt) {
      unsigned u0 = (unsigned)f2bf(Yx[tt][0]*is2) | ((unsigned)f2bf(Yx[tt][1]*is2) << 16);
      unsigned u1 = (unsigned)f2bf(Yx[tt][2]*is2) | ((unsigned)f2bf(Yx[tt][3]*is2) << 16);
      u32x2 uu; uu[0] = u0; uu[1] = u1;
      *(u32x2*)&Ybf[wid][r16][tt*16 + g*4] = uu;
      if (r16 == (tt >> 1)) {
        f32x4 yh = Yh[tt] * is1;
        *(f32x4*)&Yh1[wid][tt*16 + g*4] = yh;
      }
    }
  }
  asm volatile("s_waitcnt lgkmcnt(0)" ::: "memory");
  __builtin_amdgcn_sched_barrier(0);

  // projection: OUT[head][feat] = (Y/s2) @ We^T  (A rows 4-15 garbage, ignored)
  bf16x8 af2[4];
  #pragma unroll
  for (int kc = 0; kc < 4; ++kc)
    af2[kc] = *(const bf16x8*)&Ybf[wid][r16 & 3][kc*32 + g*8];

  #pragma unroll
  for (int tt = 0; tt < 8; ++tt) {
    f32x4 acc = (f32x4){0,0,0,0};
    #pragma unroll
    for (int kc = 0; kc < 4; ++kc) {
      bf16x8 bw = *(const bf16x8*)(webft + (long)(tt*16 + r16)*DINC + kc*32 + g*8);
      acc = __builtin_amdgcn_mfma_f32_16x16x32_bf16(af2[kc], bw, acc, 0, 0, 0);
    }
    if (g == 0) OutPl[wid][tt*16 + r16] = acc[tt >> 1];   // row tt>>1 = head of this tile
  }
  asm volatile("s_waitcnt lgkmcnt(0)" ::: "memory");
  __builtin_amdgcn_sched_barrier(0);

  if (valid) {
    int j0 = 2*lane;
    unsigned bu = hdstbfu[(long)n*64 + lane];
    out[(long)n*OUTC + j0]     = bf2f(bu & 0xffffu) + Yh1[wid][j0]   + OutPl[wid][j0];
    out[(long)n*OUTC + j0 + 1] = bf2f(bu >> 16)     + Yh1[wid][j0+1] + OutPl[wid][j0+1];
  }
}

extern "C" void kernel_launch(void* const* d_in, const int* in_sizes, int n_in,
                              void* d_out, int out_size, void* d_ws, size_t ws_size,
                              hipStream_t stream) {
  const float* X   = (const float*)d_in[0];
  const float* Xe  = (const float*)d_in[1];
  const float* Ws  = (const float*)d_in[2];
  const float* Wd  = (const float*)d_in[3];
  const float* We  = (const float*)d_in[4];
  const float* as_ = (const float*)d_in[5];
  const float* ad_ = (const float*)d_in[6];
  const float* ae_ = (const float*)d_in[7];
  const int* src   = (const int*)d_in[8];
  const int* dst   = (const int*)d_in[9];
  int N = in_sizes[0] / DINC;
  int E = in_sizes[8];
  float* out = (float*)d_out;

  char* ws = (char*)d_ws;
  auto align256 = [](size_t x){ return (x + 255) & ~(size_t)255; };
  size_t o_hsrc  = 0;                                        // bf16 [N][128]
  size_t o_hdst  = align256(o_hsrc + (size_t)N*OUTC*2);      // bf16 [N][128]
  size_t o_esrc  = align256(o_hdst + (size_t)N*OUTC*2);
  size_t o_edst  = align256(o_esrc + (size_t)N*HH*4);
  size_t o_csr   = align256(o_edst + (size_t)N*HH*4);        // u64 [E], CSR order
  size_t o_wcmb  = align256(o_csr  + (size_t)E*8);
  size_t o_webft = align256(o_wcmb + (size_t)NCMB*DINC*2);
  size_t o_veb   = align256(o_webft+ (size_t)DINC*OUTC*2);
  size_t o_deg   = align256(o_veb  + (size_t)16*DINC*2);
  size_t o_off   = align256(o_deg  + (size_t)N*4);
  size_t o_cur   = align256(o_off  + (size_t)(N+4)*4);
  size_t o_bsum  = align256(o_cur  + (size_t)N*4);
  size_t o_bpre  = align256(o_bsum + (size_t)SCAN_B*4);

  unsigned short* hsrcbf = (unsigned short*)(ws + o_hsrc);
  unsigned short* hdstbf = (unsigned short*)(ws + o_hdst);
  float* esrc  = (float*)(ws + o_esrc);
  float* edstp = (float*)(ws + o_edst);
  unsigned long long* csr = (unsigned long long*)(ws + o_csr);
  unsigned short* wcmb  = (unsigned short*)(ws + o_wcmb);
  unsigned short* webft = (unsigned short*)(ws + o_webft);
  unsigned short* veb   = (unsigned short*)(ws + o_veb);
  int* deg     = (int*)(ws + o_deg);
  int* off     = (int*)(ws + o_off);
  int* cursor  = (int*)(ws + o_cur);
  int* bsum    = (int*)(ws + o_bsum);
  int* bpre    = (int*)(ws + o_bpre);

  prep_kernel<<<32, 256, 0, stream>>>(Ws, Wd, We, as_, ad_, ae_, wcmb, webft, veb, deg, N);
  node_mfma<<<(N + 31)/32, 256, 0, stream>>>(X, wcmb, dst, deg, hsrcbf, hdstbf, esrc, edstp, N, E);
  scan1<<<SCAN_B, 256, 0, stream>>>(deg, bsum, N);
  scan2<<<1, 64, 0, stream>>>(bsum, bpre, off, N);
  scan3<<<SCAN_B, 256, 0, stream>>>(deg, bpre, off, cursor, N);
  scatter_kernel<<<(E + 255)/256, 256, 0, stream>>>(src, dst, cursor, csr, E);
  aggregate_fused<<<(N + 3)/4, 256, 0, stream>>>(Xe, veb, hsrcbf, (const unsigned*)hdstbf,
                                                 esrc, edstp, csr, off, webft, out, N);
}

// Round 11
// 443.860 us; speedup vs baseline: 1.1853x; 1.1853x over previous
//
#include <hip/hip_runtime.h>

constexpr int HH   = 4;    // heads
constexpr int DINC = 128;  // input feature dim
constexpr int OUTC = 128;  // output feature dim (H*D)
constexpr int NCMB = 272;  // combined B cols: 128 Ws | 128 Wd | 4 vs | 4 vd | 8 pad
constexpr int SCAN_B = 64;

typedef __attribute__((ext_vector_type(4))) float f32x4;
typedef __attribute__((ext_vector_type(2))) float f32x2;
typedef __attribute__((ext_vector_type(8))) short bf16x8;

__device__ __forceinline__ float leaky(float x){ return x >= 0.f ? x : 0.2f*x; }
__device__ __forceinline__ unsigned short f2bf(float f){ unsigned u=__float_as_uint(f); return (unsigned short)((u + 0x7FFFu + ((u>>16)&1u))>>16); }
__device__ __forceinline__ float bf2f(unsigned s){ return __uint_as_float(s<<16); }

// ---------------- K0: prep — element-parallel (+ deg zeroing) ----------------
__global__ __launch_bounds__(256) void prep_kernel(
    const float* __restrict__ Ws, const float* __restrict__ Wd, const float* __restrict__ We,
    const float* __restrict__ as_, const float* __restrict__ ad_, const float* __restrict__ ae_,
    unsigned short* __restrict__ wcmb, unsigned short* __restrict__ webft,
    unsigned short* __restrict__ veb, int* __restrict__ deg, int N)
{
  int tid = blockIdx.x*256 + threadIdx.x;
  int stride = gridDim.x*256;
  for (int idx = tid; idx < NCMB*DINC; idx += stride) {
    int j = idx >> 7, k = idx & 127;
    float w;
    if      (j < 128) w = Ws[j*DINC + k];
    else if (j < 256) w = Wd[(j-128)*DINC + k];
    else if (j < 260) { int h=j-256; float s=0.f; for(int d=0;d<32;++d) s += as_[h*32+d]*Ws[(h*32+d)*DINC+k]; w=s; }
    else if (j < 264) { int h=j-260; float s=0.f; for(int d=0;d<32;++d) s += ad_[h*32+d]*Wd[(h*32+d)*DINC+k]; w=s; }
    else w = 0.f;
    wcmb[idx] = f2bf(w);
  }
  for (int idx = tid; idx < 16*DINC; idx += stride) {   // veb[16][128]: 4 real head rows
    int h = idx >> 7, k = idx & 127;
    float w = 0.f;
    if (h < HH) { float s=0.f; for(int d=0;d<32;++d) s += ae_[h*32+d]*We[(h*32+d)*DINC+k]; w=s; }
    veb[idx] = f2bf(w);
  }
  for (int idx = tid; idx < DINC*OUTC; idx += stride)   // webft = We row-major bf16
    webft[idx] = f2bf(We[idx]);
  for (int idx = tid; idx < N; idx += stride) deg[idx] = 0;
}

// ---------------- K1: MFMA node GEMM C[32,272] = X @ [Ws|Wd|vs|vd]^T + fused histogram ----------------
__global__ __launch_bounds__(256) void node_mfma(
    const float* __restrict__ X, const unsigned short* __restrict__ wcmb,
    const int* __restrict__ dst, int* __restrict__ deg,
    unsigned short* __restrict__ hsrcbf, unsigned short* __restrict__ hdstbf,
    float* __restrict__ esrc, float* __restrict__ edst, int N, int E)
{
  int t = threadIdx.x;
  for (long e = (long)blockIdx.x*256 + t; e < E; e += (long)gridDim.x*256)
    atomicAdd(deg + dst[e], 1);

  int lane = t & 63, wv = t >> 6;
  int r16 = lane & 15, g = lane >> 4;
  int n0 = blockIdx.x * 32;
  int ntS = (wv*17) >> 2, ntE = ((wv+1)*17) >> 2;

  #pragma unroll
  for (int mt = 0; mt < 2; ++mt) {
    int arow = n0 + mt*16 + r16; if (arow >= N) arow = N-1;
    bf16x8 a[4];
    #pragma unroll
    for (int kc = 0; kc < 4; ++kc) {
      const float* ap = X + (long)arow*DINC + kc*32 + g*8;
      f32x4 x0 = *(const f32x4*)ap;
      f32x4 x1 = *(const f32x4*)(ap + 4);
      bf16x8 af;
      af[0]=f2bf(x0[0]); af[1]=f2bf(x0[1]); af[2]=f2bf(x0[2]); af[3]=f2bf(x0[3]);
      af[4]=f2bf(x1[0]); af[5]=f2bf(x1[1]); af[6]=f2bf(x1[2]); af[7]=f2bf(x1[3]);
      a[kc] = af;
    }
    for (int nt = ntS; nt < ntE; ++nt) {
      f32x4 acc = (f32x4){0,0,0,0};
      #pragma unroll
      for (int kc = 0; kc < 4; ++kc) {
        bf16x8 bf = *(const bf16x8*)(wcmb + (nt*16 + r16)*DINC + kc*32 + g*8);
        acc = __builtin_amdgcn_mfma_f32_16x16x32_bf16(a[kc], bf, acc, 0, 0, 0);
      }
      int j = nt*16 + r16;   // D: col = lane&15, row = g*4 + r
      #pragma unroll
      for (int r = 0; r < 4; ++r) {
        int n = n0 + mt*16 + g*4 + r;
        if (n >= N) continue;
        float v = acc[r];
        if      (j < 128) hsrcbf[(long)n*OUTC + j] = f2bf(v);
        else if (j < 256) hdstbf[(long)n*OUTC + (j-128)] = f2bf(v);
        else if (j < 260) esrc[(long)n*HH + (j-256)] = v;
        else if (j < 264) edst[(long)n*HH + (j-260)] = v;
      }
    }
  }
}

// ---------------- scan: 3-phase parallel exclusive scan of deg ----------------
__global__ __launch_bounds__(256) void scan1(const int* __restrict__ deg, int* __restrict__ bsum, int N)
{
  __shared__ int sh[256];
  int t = threadIdx.x, blk = blockIdx.x;
  int R = (N + SCAN_B*256 - 1) / (SCAN_B*256);
  int base = (blk*256 + t)*R;
  int s = 0;
  for (int i = 0; i < R; ++i) { int idx = base + i; if (idx < N) s += deg[idx]; }
  sh[t] = s; __syncthreads();
  for (int d = 128; d > 0; d >>= 1) { if (t < d) sh[t] += sh[t+d]; __syncthreads(); }
  if (t == 0) bsum[blk] = sh[0];
}

__global__ __launch_bounds__(64) void scan2(const int* __restrict__ bsum, int* __restrict__ bpre,
                                            int* __restrict__ off, int N)
{
  if (threadIdx.x == 0) {
    int r = 0;
    for (int b = 0; b < SCAN_B; ++b) { bpre[b] = r; r += bsum[b]; }
    off[N] = r;
  }
}

__global__ __launch_bounds__(256) void scan3(const int* __restrict__ deg, const int* __restrict__ bpre,
                                             int* __restrict__ off, int* __restrict__ cursor, int N)
{
  __shared__ int sh[256];
  int t = threadIdx.x, blk = blockIdx.x;
  int R = (N + SCAN_B*256 - 1) / (SCAN_B*256);
  int base = (blk*256 + t)*R;
  int s = 0;
  for (int i = 0; i < R; ++i) { int idx = base + i; if (idx < N) s += deg[idx]; }
  sh[t] = s; __syncthreads();
  for (int d = 1; d < 256; d <<= 1) {
    int v = (t >= d) ? sh[t-d] : 0;
    __syncthreads();
    sh[t] += v;
    __syncthreads();
  }
  int r = bpre[blk] + sh[t] - s;
  for (int i = 0; i < R; ++i) {
    int idx = base + i;
    if (idx < N) { off[idx] = r; cursor[idx] = r; r += deg[idx]; }
  }
}

// ---------------- scatter: 8B CSR records {src, eid} ----------------
__global__ __launch_bounds__(256) void scatter_kernel(
    const int* __restrict__ src, const int* __restrict__ dst,
    int* __restrict__ cursor, unsigned long long* __restrict__ csr, int E)
{
  int e = blockIdx.x*256 + threadIdx.x;
  if (e >= E) return;
  int p = atomicAdd(cursor + dst[e], 1);
  csr[p] = ((unsigned long long)(unsigned)src[e] << 32) | (unsigned)e;
}

// ---------------- K4: FUSED per-node aggregation (R9 structure + hoisted coefs + MFMA epilogue) ----------------
// Wave = node. Phase A per 16-edge chunk: gather Xe rows as MFMA A-frags, logit MFMA,
// nu1 (64 lanes: edge r16 x head g) and nu2 -> LDS; denominators accumulated in registers.
// Phase B: lean streaming (no exp, no esrc). Epilogue: Y@We^T on MFMA pipe.
// All LDS wave-local: no block barriers; epilogue LDS unioned over dead chunk buffers.
__global__ __launch_bounds__(256) void aggregate_fused(
    const float* __restrict__ Xe, const unsigned short* __restrict__ veb,
    const unsigned* __restrict__ hsrcbfu, const unsigned* __restrict__ hdstbfu,
    const float* __restrict__ esrc, const float* __restrict__ edst,
    const unsigned long long* __restrict__ csr, const int* __restrict__ off,
    const unsigned short* __restrict__ webft, float* __restrict__ out, int N)
{
  struct WaveA {
    unsigned short XeL[16][136];  // bf16 Xe rows (pad 8)
    float S12[16][12];            // [i][0..3]=nu1 per head, [i][4..7]=nu2, pad
    int srcL[16];
  };
  struct WaveB {
    unsigned short Ybf[HH][136];  // bf16 Y (edge path), pre-scaled by 1/s2
    float OutPl[136];             // projected edge-path output
  };
  union WaveLds { WaveA a; WaveB b; };
  __shared__ WaveLds L[4];

  int t = threadIdx.x, wid = t >> 6, lane = t & 63;
  int r16 = lane & 15, g = lane >> 4;
  int n = blockIdx.x*4 + wid;
  bool valid = (n < N);
  int beg = 0, end = 0;
  if (valid) { beg = off[n]; end = off[n+1]; }
  int hl = g;                  // head owned by this lane in Phase B
  int j0 = 2*lane;             // 2 output cols owned by this lane
  f32x4 edh4 = valid ? *(const f32x4*)(edst + (long)n*HH) : (f32x4){0,0,0,0};

  bf16x8 vebf[4];
  #pragma unroll
  for (int kc = 0; kc < 4; ++kc)
    vebf[kc] = *(const bf16x8*)(veb + r16*DINC + kc*32 + g*8);

  f32x2 acc = {0.f,0.f};
  f32x2 Y0={0,0}, Y1={0,0}, Y2={0,0}, Y3={0,0};
  float s1s = 0.f, s2s = 0.f;

  for (int p0 = beg; p0 < end; p0 += 16) {
    int cnt = min(16, end - p0);
    // --- Phase A ---
    long pr = (long)p0 + r16; if (pr >= end) pr = end - 1;
    unsigned long long pk = csr[pr];
    int s_ = (int)(pk >> 32);
    long eid = (long)(unsigned)pk;
    if (lane < 16) L[wid].a.srcL[lane] = s_;

    // nu1 for (edge r16, head g) — all 64 lanes
    float es = esrc[(long)s_*HH + g];
    float n1 = ((p0 + r16) < end) ? __expf(leaky(es + edh4[g])) : 0.f;
    L[wid].a.S12[r16][g] = n1;
    s1s += n1;

    f32x4 accq = (f32x4){0,0,0,0};
    #pragma unroll
    for (int kc = 0; kc < 4; ++kc) {
      const float* ap = Xe + eid*DINC + kc*32 + g*8;
      f32x4 x0 = *(const f32x4*)ap;
      f32x4 x1 = *(const f32x4*)(ap + 4);
      bf16x8 af;
      af[0]=f2bf(x0[0]); af[1]=f2bf(x0[1]); af[2]=f2bf(x0[2]); af[3]=f2bf(x0[3]);
      af[4]=f2bf(x1[0]); af[5]=f2bf(x1[1]); af[6]=f2bf(x1[2]); af[7]=f2bf(x1[3]);
      *(bf16x8*)&L[wid].a.XeL[r16][kc*32 + g*8] = af;
      accq = __builtin_amdgcn_mfma_f32_16x16x32_bf16(af, vebf[kc], accq, 0, 0, 0);
    }
    if (r16 < HH) {            // logits D: col r16 = head, row g*4+r = edge-in-chunk
      #pragma unroll
      for (int r = 0; r < 4; ++r) {
        float n2 = ((p0 + g*4 + r) < end) ? __expf(leaky(accq[r] + edh4[r16])) : 0.f;
        L[wid].a.S12[g*4 + r][4 + r16] = n2;
        s2s += n2;
      }
    }
    asm volatile("s_waitcnt lgkmcnt(0)" ::: "memory");
    __builtin_amdgcn_sched_barrier(0);

    // --- Phase B: lean stream ---
    int i = 0;
    for (; i + 2 <= cnt; i += 2) {
      int sa = L[wid].a.srcL[i], sb = L[wid].a.srcL[i+1];
      f32x4 nua = *(const f32x4*)&L[wid].a.S12[i][4];
      f32x4 nub = *(const f32x4*)&L[wid].a.S12[i+1][4];
      float n1a = L[wid].a.S12[i][hl];
      float n1b = L[wid].a.S12[i+1][hl];
      unsigned xua = *(const unsigned*)&L[wid].a.XeL[i][j0];
      unsigned xub = *(const unsigned*)&L[wid].a.XeL[i+1][j0];
      unsigned hua = hsrcbfu[(long)sa*64 + lane];
      unsigned hub = hsrcbfu[(long)sb*64 + lane];
      f32x2 xa; xa[0] = bf2f(xua & 0xffffu); xa[1] = bf2f(xua >> 16);
      f32x2 xb; xb[0] = bf2f(xub & 0xffffu); xb[1] = bf2f(xub >> 16);
      f32x2 ha; ha[0] = bf2f(hua & 0xffffu); ha[1] = bf2f(hua >> 16);
      f32x2 hb; hb[0] = bf2f(hub & 0xffffu); hb[1] = bf2f(hub >> 16);
      acc += n1a*ha + n1b*hb;
      Y0 += nua[0]*xa + nub[0]*xb;
      Y1 += nua[1]*xa + nub[1]*xb;
      Y2 += nua[2]*xa + nub[2]*xb;
      Y3 += nua[3]*xa + nub[3]*xb;
    }
    if (i < cnt) {
      int sa = L[wid].a.srcL[i];
      f32x4 nua = *(const f32x4*)&L[wid].a.S12[i][4];
      float n1a = L[wid].a.S12[i][hl];
      unsigned xua = *(const unsigned*)&L[wid].a.XeL[i][j0];
      unsigned hua = hsrcbfu[(long)sa*64 + lane];
      f32x2 xa; xa[0] = bf2f(xua & 0xffffu); xa[1] = bf2f(xua >> 16);
      f32x2 ha; ha[0] = bf2f(hua & 0xffffu); ha[1] = bf2f(hua >> 16);
      acc += n1a*ha;
      Y0 += nua[0]*xa; Y1 += nua[1]*xa; Y2 += nua[2]*xa; Y3 += nua[3]*xa;
    }
    asm volatile("" ::: "memory");
  }

  // denominators: s1 per head g across r16; s2 at lanes r16<4 across g
  s1s += __shfl_xor(s1s, 1, 64); s1s += __shfl_xor(s1s, 2, 64);
  s1s += __shfl_xor(s1s, 4, 64); s1s += __shfl_xor(s1s, 8, 64);
  s2s += __shfl_xor(s2s, 16, 64); s2s += __shfl_xor(s2s, 32, 64);
  float is1h = (s1s != 0.f) ? 1.f/s1s : 0.f;
  f32x4 is2v;
  #pragma unroll
  for (int h = 0; h < HH; ++h) {
    float v = __shfl(s2s, h, 64);
    is2v[h] = (v != 0.f) ? 1.f/v : 0.f;
  }
  acc *= is1h;
  Y0 *= is2v[0]; Y1 *= is2v[1]; Y2 *= is2v[2]; Y3 *= is2v[3];

  asm volatile("s_waitcnt lgkmcnt(0)" ::: "memory");   // drain Phase-B reads before union reuse
  __builtin_amdgcn_sched_barrier(0);

  // Y -> bf16 LDS [head][feat]
  {
    unsigned u0 = (unsigned)f2bf(Y0[0]) | ((unsigned)f2bf(Y0[1]) << 16);
    unsigned u1 = (unsigned)f2bf(Y1[0]) | ((unsigned)f2bf(Y1[1]) << 16);
    unsigned u2 = (unsigned)f2bf(Y2[0]) | ((unsigned)f2bf(Y2[1]) << 16);
    unsigned u3 = (unsigned)f2bf(Y3[0]) | ((unsigned)f2bf(Y3[1]) << 16);
    *(unsigned*)&L[wid].b.Ybf[0][j0] = u0;
    *(unsigned*)&L[wid].b.Ybf[1][j0] = u1;
    *(unsigned*)&L[wid].b.Ybf[2][j0] = u2;
    *(unsigned*)&L[wid].b.Ybf[3][j0] = u3;
  }
  asm volatile("s_waitcnt lgkmcnt(0)" ::: "memory");
  __builtin_amdgcn_sched_barrier(0);

  // projection on MFMA: OUT[head][feat] = Y @ We^T; keep diagonal head = feat>>5
  bf16x8 af2[4];
  #pragma unroll
  for (int kc = 0; kc < 4; ++kc)
    af2[kc] = *(const bf16x8*)&L[wid].b.Ybf[r16 & 3][kc*32 + g*8];

  #pragma unroll
  for (int tt = 0; tt < 8; ++tt) {
    f32x4 pacc = (f32x4){0,0,0,0};
    #pragma unroll
    for (int kc = 0; kc < 4; ++kc) {
      bf16x8 bw = *(const bf16x8*)(webft + (long)(tt*16 + r16)*DINC + kc*32 + g*8);
      pacc = __builtin_amdgcn_mfma_f32_16x16x32_bf16(af2[kc], bw, pacc, 0, 0, 0);
    }
    if (g == 0) L[wid].b.OutPl[tt*16 + r16] = pacc[tt >> 1];  // row tt>>1 = head of this tile
  }
  asm volatile("s_waitcnt lgkmcnt(0)" ::: "memory");
  __builtin_amdgcn_sched_barrier(0);

  if (valid) {
    unsigned bu = hdstbfu[(long)n*64 + lane];
    out[(long)n*OUTC + j0]     = bf2f(bu & 0xffffu) + acc[0] + L[wid].b.OutPl[j0];
    out[(long)n*OUTC + j0 + 1] = bf2f(bu >> 16)     + acc[1] + L[wid].b.OutPl[j0+1];
  }
}

extern "C" void kernel_launch(void* const* d_in, const int* in_sizes, int n_in,
                              void* d_out, int out_size, void* d_ws, size_t ws_size,
                              hipStream_t stream) {
  const float* X   = (const float*)d_in[0];
  const float* Xe  = (const float*)d_in[1];
  const float* Ws  = (const float*)d_in[2];
  const float* Wd  = (const float*)d_in[3];
  const float* We  = (const float*)d_in[4];
  const float* as_ = (const float*)d_in[5];
  const float* ad_ = (const float*)d_in[6];
  const float* ae_ = (const float*)d_in[7];
  const int* src   = (const int*)d_in[8];
  const int* dst   = (const int*)d_in[9];
  int N = in_sizes[0] / DINC;
  int E = in_sizes[8];
  float* out = (float*)d_out;

  char* ws = (char*)d_ws;
  auto align256 = [](size_t x){ return (x + 255) & ~(size_t)255; };
  size_t o_hsrc  = 0;                                        // bf16 [N][128]
  size_t o_hdst  = align256(o_hsrc + (size_t)N*OUTC*2);      // bf16 [N][128]
  size_t o_esrc  = align256(o_hdst + (size_t)N*OUTC*2);
  size_t o_edst  = align256(o_esrc + (size_t)N*HH*4);
  size_t o_csr   = align256(o_edst + (size_t)N*HH*4);        // u64 [E], CSR order
  size_t o_wcmb  = align256(o_csr  + (size_t)E*8);
  size_t o_webft = align256(o_wcmb + (size_t)NCMB*DINC*2);
  size_t o_veb   = align256(o_webft+ (size_t)DINC*OUTC*2);
  size_t o_deg   = align256(o_veb  + (size_t)16*DINC*2);
  size_t o_off   = align256(o_deg  + (size_t)N*4);
  size_t o_cur   = align256(o_off  + (size_t)(N+4)*4);
  size_t o_bsum  = align256(o_cur  + (size_t)N*4);
  size_t o_bpre  = align256(o_bsum + (size_t)SCAN_B*4);

  unsigned short* hsrcbf = (unsigned short*)(ws + o_hsrc);
  unsigned short* hdstbf = (unsigned short*)(ws + o_hdst);
  float* esrc  = (float*)(ws + o_esrc);
  float* edstp = (float*)(ws + o_edst);
  unsigned long long* csr = (unsigned long long*)(ws + o_csr);
  unsigned short* wcmb  = (unsigned short*)(ws + o_wcmb);
  unsigned short* webft = (unsigned short*)(ws + o_webft);
  unsigned short* veb   = (unsigned short*)(ws + o_veb);
  int* deg     = (int*)(ws + o_deg);
  int* off     = (int*)(ws + o_off);
  int* cursor  = (int*)(ws + o_cur);
  int* bsum    = (int*)(ws + o_bsum);
  int* bpre    = (int*)(ws + o_bpre);

  prep_kernel<<<32, 256, 0, stream>>>(Ws, Wd, We, as_, ad_, ae_, wcmb, webft, veb, deg, N);
  node_mfma<<<(N + 31)/32, 256, 0, stream>>>(X, wcmb, dst, deg, hsrcbf, hdstbf, esrc, edstp, N, E);
  scan1<<<SCAN_B, 256, 0, stream>>>(deg, bsum, N);
  scan2<<<1, 64, 0, stream>>>(bsum, bpre, off, N);
  scan3<<<SCAN_B, 256, 0, stream>>>(deg, bpre, off, cursor, N);
  scatter_kernel<<<(E + 255)/256, 256, 0, stream>>>(src, dst, cursor, csr, E);
  aggregate_fused<<<(N + 3)/4, 256, 0, stream>>>(Xe, veb, (const unsigned*)hsrcbf, (const unsigned*)hdstbf,
                                                 esrc, edstp, csr, off, webft, out, N);
}

// Round 12
// 414.402 us; speedup vs baseline: 1.2696x; 1.0711x over previous
//
#include <hip/hip_runtime.h>

constexpr int HH   = 4;    // heads
constexpr int DINC = 128;  // input feature dim
constexpr int OUTC = 128;  // output feature dim (H*D)
constexpr int NCMB = 272;  // combined B cols: 128 Ws | 128 Wd | 4 vs | 4 vd | 8 pad
constexpr int SCAN_B = 64;

typedef __attribute__((ext_vector_type(4))) float f32x4;
typedef __attribute__((ext_vector_type(2))) float f32x2;
typedef __attribute__((ext_vector_type(8))) short bf16x8;

__device__ __forceinline__ float leaky(float x){ return x >= 0.f ? x : 0.2f*x; }
__device__ __forceinline__ unsigned short f2bf(float f){ unsigned u=__float_as_uint(f); return (unsigned short)((u + 0x7FFFu + ((u>>16)&1u))>>16); }
__device__ __forceinline__ float bf2f(unsigned s){ return __uint_as_float(s<<16); }

// ---------------- K0: prep — element-parallel (+ deg zeroing) ----------------
__global__ __launch_bounds__(256) void prep_kernel(
    const float* __restrict__ Ws, const float* __restrict__ Wd, const float* __restrict__ We,
    const float* __restrict__ as_, const float* __restrict__ ad_, const float* __restrict__ ae_,
    unsigned short* __restrict__ wcmb, unsigned short* __restrict__ webf,
    unsigned short* __restrict__ veb, int* __restrict__ deg, int N)
{
  int tid = blockIdx.x*256 + threadIdx.x;
  int stride = gridDim.x*256;
  for (int idx = tid; idx < NCMB*DINC; idx += stride) {
    int j = idx >> 7, k = idx & 127;
    float w;
    if      (j < 128) w = Ws[j*DINC + k];
    else if (j < 256) w = Wd[(j-128)*DINC + k];
    else if (j < 260) { int h=j-256; float s=0.f; for(int d=0;d<32;++d) s += as_[h*32+d]*Ws[(h*32+d)*DINC+k]; w=s; }
    else if (j < 264) { int h=j-260; float s=0.f; for(int d=0;d<32;++d) s += ad_[h*32+d]*Wd[(h*32+d)*DINC+k]; w=s; }
    else w = 0.f;
    wcmb[idx] = f2bf(w);
  }
  for (int idx = tid; idx < 16*DINC; idx += stride) {   // veb[16][128]: 4 real head rows
    int h = idx >> 7, k = idx & 127;
    float w = 0.f;
    if (h < HH) { float s=0.f; for(int d=0;d<32;++d) s += ae_[h*32+d]*We[(h*32+d)*DINC+k]; w=s; }
    veb[idx] = f2bf(w);
  }
  for (int idx = tid; idx < DINC*OUTC; idx += stride) { // webf[k][j] = We[j][k]  (col-major, R9 layout)
    int k = idx >> 7, j = idx & 127;
    webf[idx] = f2bf(We[j*DINC + k]);
  }
  for (int idx = tid; idx < N; idx += stride) deg[idx] = 0;
}

// ---------------- K1: MFMA node GEMM C[32,272] = X @ [Ws|Wd|vs|vd]^T + fused histogram ----------------
__global__ __launch_bounds__(256) void node_mfma(
    const float* __restrict__ X, const unsigned short* __restrict__ wcmb,
    const int* __restrict__ dst, int* __restrict__ deg,
    unsigned short* __restrict__ hsrcbf, unsigned short* __restrict__ hdstbf,
    float* __restrict__ esrc, float* __restrict__ edst, int N, int E)
{
  int t = threadIdx.x;
  for (long e = (long)blockIdx.x*256 + t; e < E; e += (long)gridDim.x*256)
    atomicAdd(deg + dst[e], 1);

  int lane = t & 63, wv = t >> 6;
  int r16 = lane & 15, g = lane >> 4;
  int n0 = blockIdx.x * 32;
  int ntS = (wv*17) >> 2, ntE = ((wv+1)*17) >> 2;

  #pragma unroll
  for (int mt = 0; mt < 2; ++mt) {
    int arow = n0 + mt*16 + r16; if (arow >= N) arow = N-1;
    bf16x8 a[4];
    #pragma unroll
    for (int kc = 0; kc < 4; ++kc) {
      const float* ap = X + (long)arow*DINC + kc*32 + g*8;
      f32x4 x0 = *(const f32x4*)ap;
      f32x4 x1 = *(const f32x4*)(ap + 4);
      bf16x8 af;
      af[0]=f2bf(x0[0]); af[1]=f2bf(x0[1]); af[2]=f2bf(x0[2]); af[3]=f2bf(x0[3]);
      af[4]=f2bf(x1[0]); af[5]=f2bf(x1[1]); af[6]=f2bf(x1[2]); af[7]=f2bf(x1[3]);
      a[kc] = af;
    }
    for (int nt = ntS; nt < ntE; ++nt) {
      f32x4 acc = (f32x4){0,0,0,0};
      #pragma unroll
      for (int kc = 0; kc < 4; ++kc) {
        bf16x8 bf = *(const bf16x8*)(wcmb + (nt*16 + r16)*DINC + kc*32 + g*8);
        acc = __builtin_amdgcn_mfma_f32_16x16x32_bf16(a[kc], bf, acc, 0, 0, 0);
      }
      int j = nt*16 + r16;   // D: col = lane&15, row = g*4 + r
      #pragma unroll
      for (int r = 0; r < 4; ++r) {
        int n = n0 + mt*16 + g*4 + r;
        if (n >= N) continue;
        float v = acc[r];
        if      (j < 128) hsrcbf[(long)n*OUTC + j] = f2bf(v);
        else if (j < 256) hdstbf[(long)n*OUTC + (j-128)] = f2bf(v);
        else if (j < 260) esrc[(long)n*HH + (j-256)] = v;
        else if (j < 264) edst[(long)n*HH + (j-260)] = v;
      }
    }
  }
}

// ---------------- scan: 3-phase parallel exclusive scan of deg ----------------
__global__ __launch_bounds__(256) void scan1(const int* __restrict__ deg, int* __restrict__ bsum, int N)
{
  __shared__ int sh[256];
  int t = threadIdx.x, blk = blockIdx.x;
  int R = (N + SCAN_B*256 - 1) / (SCAN_B*256);
  int base = (blk*256 + t)*R;
  int s = 0;
  for (int i = 0; i < R; ++i) { int idx = base + i; if (idx < N) s += deg[idx]; }
  sh[t] = s; __syncthreads();
  for (int d = 128; d > 0; d >>= 1) { if (t < d) sh[t] += sh[t+d]; __syncthreads(); }
  if (t == 0) bsum[blk] = sh[0];
}

__global__ __launch_bounds__(64) void scan2(const int* __restrict__ bsum, int* __restrict__ bpre,
                                            int* __restrict__ off, int N)
{
  if (threadIdx.x == 0) {
    int r = 0;
    for (int b = 0; b < SCAN_B; ++b) { bpre[b] = r; r += bsum[b]; }
    off[N] = r;
  }
}

__global__ __launch_bounds__(256) void scan3(const int* __restrict__ deg, const int* __restrict__ bpre,
                                             int* __restrict__ off, int* __restrict__ cursor, int N)
{
  __shared__ int sh[256];
  int t = threadIdx.x, blk = blockIdx.x;
  int R = (N + SCAN_B*256 - 1) / (SCAN_B*256);
  int base = (blk*256 + t)*R;
  int s = 0;
  for (int i = 0; i < R; ++i) { int idx = base + i; if (idx < N) s += deg[idx]; }
  sh[t] = s; __syncthreads();
  for (int d = 1; d < 256; d <<= 1) {
    int v = (t >= d) ? sh[t-d] : 0;
    __syncthreads();
    sh[t] += v;
    __syncthreads();
  }
  int r = bpre[blk] + sh[t] - s;
  for (int i = 0; i < R; ++i) {
    int idx = base + i;
    if (idx < N) { off[idx] = r; cursor[idx] = r; r += deg[idx]; }
  }
}

// ---------------- scatter: 8B CSR records {src, eid} ----------------
__global__ __launch_bounds__(256) void scatter_kernel(
    const int* __restrict__ src, const int* __restrict__ dst,
    int* __restrict__ cursor, unsigned long long* __restrict__ csr, int E)
{
  int e = blockIdx.x*256 + threadIdx.x;
  if (e >= E) return;
  int p = atomicAdd(cursor + dst[e], 1);
  csr[p] = ((unsigned long long)(unsigned)src[e] << 32) | (unsigned)e;
}

// ---------------- K4: FUSED per-node aggregation (R9 bodies, fences removed, persistent) ----------------
// Wave = node (grid-stride). Per 16-edge chunk: Phase A gathers Xe rows as MFMA A-frags ->
// LDS + logit MFMA + nu2; Phase B streams the chunk from LDS. NO manual fences: all LDS is
// wave-local, DS ops are in-order per wave, compiler inserts waits — so it may hoist the
// next chunk/node's global loads above Phase B (software pipelining).
// Ylds is unioned over XeL (dead after last Phase B) -> 18.7 KB/block -> 8 blocks/CU.
__global__ __launch_bounds__(256) void aggregate_fused(
    const float* __restrict__ Xe, const unsigned short* __restrict__ veb,
    const unsigned* __restrict__ hsrcbfu, const unsigned* __restrict__ hdstbfu,
    const float* __restrict__ esrc, const float* __restrict__ edst,
    const unsigned long long* __restrict__ csr, const int* __restrict__ off,
    const unsigned short* __restrict__ webf, float* __restrict__ out, int N)
{
  struct WaveLds {
    union {
      unsigned short XeL[16][DINC+8];   // 4352 B: bf16 Xe rows of current chunk
      float Ylds[HH][DINC+4];           // 2112 B: Y for epilogue (reuses dead XeL)
    };
    float S2[16][HH];                   // nu2 per (edge-in-chunk, head)
    int srcL[16];
  };
  __shared__ WaveLds L[4];

  int t = threadIdx.x, wid = t >> 6, lane = t & 63;
  int r16 = lane & 15, g = lane >> 4;
  int hl = g;                  // head owned by this lane (cols 2*lane)
  int j0 = 2*lane;

  bf16x8 vebf[4];
  #pragma unroll
  for (int kc = 0; kc < 4; ++kc)
    vebf[kc] = *(const bf16x8*)(veb + r16*DINC + kc*32 + g*8);

  for (int n = blockIdx.x*4 + wid; n < N; n += gridDim.x*4) {
    int beg = off[n], end = off[n+1];
    unsigned bu = hdstbfu[(long)n*64 + lane];            // early: overlaps chunk loop
    f32x4 edh4 = *(const f32x4*)(edst + (long)n*HH);
    float edh  = edh4[hl];
    float edhr = edh4[r16 & 3];

    f32x2 acc = {0.f,0.f};
    f32x2 Y0={0,0}, Y1={0,0}, Y2={0,0}, Y3={0,0};
    float s1h = 0.f;
    f32x4 s2v = {0,0,0,0};

    for (int p0 = beg; p0 < end; p0 += 16) {
      int cnt = min(16, end - p0);
      // --- Phase A: csr entry, Xe row gather -> A-frags -> LDS + MFMA logits ---
      long pr = (long)p0 + r16; if (pr >= end) pr = end - 1;
      unsigned long long pk = csr[pr];
      long eid = (long)(unsigned)pk;
      if (lane < 16) L[wid].srcL[lane] = (int)(pk >> 32);

      f32x4 accq = (f32x4){0,0,0,0};
      #pragma unroll
      for (int kc = 0; kc < 4; ++kc) {
        const float* ap = Xe + eid*DINC + kc*32 + g*8;
        f32x4 x0 = *(const f32x4*)ap;
        f32x4 x1 = *(const f32x4*)(ap + 4);
        bf16x8 af;
        af[0]=f2bf(x0[0]); af[1]=f2bf(x0[1]); af[2]=f2bf(x0[2]); af[3]=f2bf(x0[3]);
        af[4]=f2bf(x1[0]); af[5]=f2bf(x1[1]); af[6]=f2bf(x1[2]); af[7]=f2bf(x1[3]);
        *(bf16x8*)&L[wid].XeL[r16][kc*32 + g*8] = af;
        accq = __builtin_amdgcn_mfma_f32_16x16x32_bf16(af, vebf[kc], accq, 0, 0, 0);
      }
      if (r16 < HH) {            // logits D: col r16 = head, row g*4+r = edge-in-chunk
        #pragma unroll
        for (int r = 0; r < 4; ++r) {
          float n2 = ((p0 + g*4 + r) < end) ? __expf(leaky(accq[r] + edhr)) : 0.f;
          L[wid].S2[g*4 + r][r16] = n2;
        }
      }

      // --- Phase B: stream the chunk's edges from LDS (compiler-ordered, wave-local) ---
      for (int i = 0; i < cnt; ++i) {
        int s_ = L[wid].srcL[i];
        f32x4 nu2 = *(const f32x4*)L[wid].S2[i];
        unsigned xu = *(const unsigned*)&L[wid].XeL[i][j0];
        unsigned hu = hsrcbfu[(long)s_*64 + lane];
        float es_ = esrc[(long)s_*HH + hl];
        float n1 = __expf(leaky(es_ + edh));
        f32x2 xe; xe[0] = bf2f(xu & 0xffffu); xe[1] = bf2f(xu >> 16);
        f32x2 hs; hs[0] = bf2f(hu & 0xffffu); hs[1] = bf2f(hu >> 16);
        s1h += n1; s2v += nu2;
        acc += n1*hs;
        Y0 += nu2[0]*xe; Y1 += nu2[1]*xe; Y2 += nu2[2]*xe; Y3 += nu2[3]*xe;
      }
    }

    float is1h = (s1h != 0.f) ? 1.f / s1h : 0.f;
    f32x4 is2;
    #pragma unroll
    for (int h=0; h<HH; ++h) is2[h] = (s2v[h] != 0.f) ? 1.f / s2v[h] : 0.f;
    acc *= is1h;
    Y0 *= is2[0]; Y1 *= is2[1]; Y2 *= is2[2]; Y3 *= is2[3];

    // Y -> LDS (overlays dead XeL; in-order DS per wave makes this safe)
    *(f32x2*)&L[wid].Ylds[0][j0] = Y0;
    *(f32x2*)&L[wid].Ylds[1][j0] = Y1;
    *(f32x2*)&L[wid].Ylds[2][j0] = Y2;
    *(f32x2*)&L[wid].Ylds[3][j0] = Y3;

    // finish: out[n,j] = h_dst + acc + sum_k Y[hl][k]*We[j,k]  (webf[k][j] bf16, L1-resident)
    const float* yp = L[wid].Ylds[hl];
    float f0 = 0.f, f1 = 0.f;
    #pragma unroll 8
    for (int k = 0; k < DINC; ++k) {
      unsigned wu = *(const unsigned*)(webf + k*OUTC + j0);
      float y = yp[k];
      f0 += y * bf2f(wu & 0xffffu);
      f1 += y * bf2f(wu >> 16);
    }
    out[(long)n*OUTC + j0]     = bf2f(bu & 0xffffu) + acc[0] + f0;
    out[(long)n*OUTC + j0 + 1] = bf2f(bu >> 16)     + acc[1] + f1;
  }
}

extern "C" void kernel_launch(void* const* d_in, const int* in_sizes, int n_in,
                              void* d_out, int out_size, void* d_ws, size_t ws_size,
                              hipStream_t stream) {
  const float* X   = (const float*)d_in[0];
  const float* Xe  = (const float*)d_in[1];
  const float* Ws  = (const float*)d_in[2];
  const float* Wd  = (const float*)d_in[3];
  const float* We  = (const float*)d_in[4];
  const float* as_ = (const float*)d_in[5];
  const float* ad_ = (const float*)d_in[6];
  const float* ae_ = (const float*)d_in[7];
  const int* src   = (const int*)d_in[8];
  const int* dst   = (const int*)d_in[9];
  int N = in_sizes[0] / DINC;
  int E = in_sizes[8];
  float* out = (float*)d_out;

  char* ws = (char*)d_ws;
  auto align256 = [](size_t x){ return (x + 255) & ~(size_t)255; };
  size_t o_hsrc  = 0;                                        // bf16 [N][128]
  size_t o_hdst  = align256(o_hsrc + (size_t)N*OUTC*2);      // bf16 [N][128]
  size_t o_esrc  = align256(o_hdst + (size_t)N*OUTC*2);
  size_t o_edst  = align256(o_esrc + (size_t)N*HH*4);
  size_t o_csr   = align256(o_edst + (size_t)N*HH*4);        // u64 [E], CSR order
  size_t o_wcmb  = align256(o_csr  + (size_t)E*8);
  size_t o_webf  = align256(o_wcmb + (size_t)NCMB*DINC*2);
  size_t o_veb   = align256(o_webf + (size_t)DINC*OUTC*2);
  size_t o_deg   = align256(o_veb  + (size_t)16*DINC*2);
  size_t o_off   = align256(o_deg  + (size_t)N*4);
  size_t o_cur   = align256(o_off  + (size_t)(N+4)*4);
  size_t o_bsum  = align256(o_cur  + (size_t)N*4);
  size_t o_bpre  = align256(o_bsum + (size_t)SCAN_B*4);

  unsigned short* hsrcbf = (unsigned short*)(ws + o_hsrc);
  unsigned short* hdstbf = (unsigned short*)(ws + o_hdst);
  float* esrc  = (float*)(ws + o_esrc);
  float* edstp = (float*)(ws + o_edst);
  unsigned long long* csr = (unsigned long long*)(ws + o_csr);
  unsigned short* wcmb = (unsigned short*)(ws + o_wcmb);
  unsigned short* webf = (unsigned short*)(ws + o_webf);
  unsigned short* veb  = (unsigned short*)(ws + o_veb);
  int* deg     = (int*)(ws + o_deg);
  int* off     = (int*)(ws + o_off);
  int* cursor  = (int*)(ws + o_cur);
  int* bsum    = (int*)(ws + o_bsum);
  int* bpre    = (int*)(ws + o_bpre);

  prep_kernel<<<32, 256, 0, stream>>>(Ws, Wd, We, as_, ad_, ae_, wcmb, webf, veb, deg, N);
  node_mfma<<<(N + 31)/32, 256, 0, stream>>>(X, wcmb, dst, deg, hsrcbf, hdstbf, esrc, edstp, N, E);
  scan1<<<SCAN_B, 256, 0, stream>>>(deg, bsum, N);
  scan2<<<1, 64, 0, stream>>>(bsum, bpre, off, N);
  scan3<<<SCAN_B, 256, 0, stream>>>(deg, bpre, off, cursor, N);
  scatter_kernel<<<(E + 255)/256, 256, 0, stream>>>(src, dst, cursor, csr, E);
  int nbAgg = (N + 3) / 4; if (nbAgg > 2048) nbAgg = 2048;
  aggregate_fused<<<nbAgg, 256, 0, stream>>>(Xe, veb, (const unsigned*)hsrcbf, (const unsigned*)hdstbf,
                                             esrc, edstp, csr, off, webf, out, N);
}

// Round 13
// 413.296 us; speedup vs baseline: 1.2730x; 1.0027x over previous
//
#include <hip/hip_runtime.h>

constexpr int HH   = 4;    // heads
constexpr int DINC = 128;  // input feature dim
constexpr int OUTC = 128;  // output feature dim (H*D)
constexpr int NCMB = 272;  // combined B cols: 128 Ws | 128 Wd | 4 vs | 4 vd | 8 pad
constexpr int SCAN_B = 64;

typedef __attribute__((ext_vector_type(4))) float f32x4;
typedef __attribute__((ext_vector_type(2))) float f32x2;
typedef __attribute__((ext_vector_type(8))) short bf16x8;

__device__ __forceinline__ float leaky(float x){ return x >= 0.f ? x : 0.2f*x; }
__device__ __forceinline__ unsigned short f2bf(float f){ unsigned u=__float_as_uint(f); return (unsigned short)((u + 0x7FFFu + ((u>>16)&1u))>>16); }
__device__ __forceinline__ float bf2f(unsigned s){ return __uint_as_float(s<<16); }

// ---------------- K0: prep — element-parallel (+ deg zeroing) ----------------
__global__ __launch_bounds__(256) void prep_kernel(
    const float* __restrict__ Ws, const float* __restrict__ Wd, const float* __restrict__ We,
    const float* __restrict__ as_, const float* __restrict__ ad_, const float* __restrict__ ae_,
    unsigned short* __restrict__ wcmb, unsigned short* __restrict__ webf,
    unsigned short* __restrict__ veb, int* __restrict__ deg, int N)
{
  int tid = blockIdx.x*256 + threadIdx.x;
  int stride = gridDim.x*256;
  for (int idx = tid; idx < NCMB*DINC; idx += stride) {
    int j = idx >> 7, k = idx & 127;
    float w;
    if      (j < 128) w = Ws[j*DINC + k];
    else if (j < 256) w = Wd[(j-128)*DINC + k];
    else if (j < 260) { int h=j-256; float s=0.f; for(int d=0;d<32;++d) s += as_[h*32+d]*Ws[(h*32+d)*DINC+k]; w=s; }
    else if (j < 264) { int h=j-260; float s=0.f; for(int d=0;d<32;++d) s += ad_[h*32+d]*Wd[(h*32+d)*DINC+k]; w=s; }
    else w = 0.f;
    wcmb[idx] = f2bf(w);
  }
  for (int idx = tid; idx < 16*DINC; idx += stride) {   // veb[16][128]: 4 real head rows
    int h = idx >> 7, k = idx & 127;
    float w = 0.f;
    if (h < HH) { float s=0.f; for(int d=0;d<32;++d) s += ae_[h*32+d]*We[(h*32+d)*DINC+k]; w=s; }
    veb[idx] = f2bf(w);
  }
  for (int idx = tid; idx < DINC*OUTC; idx += stride) { // webf[k][j] = We[j][k]
    int k = idx >> 7, j = idx & 127;
    webf[idx] = f2bf(We[j*DINC + k]);
  }
  for (int idx = tid; idx < N; idx += stride) deg[idx] = 0;
}

// ---------------- K1: MFMA node GEMM C[32,272] = X @ [Ws|Wd|vs|vd]^T + fused histogram ----------------
__global__ __launch_bounds__(256) void node_mfma(
    const float* __restrict__ X, const unsigned short* __restrict__ wcmb,
    const int* __restrict__ dst, int* __restrict__ deg,
    unsigned short* __restrict__ hsrcbf, unsigned short* __restrict__ hdstbf,
    float* __restrict__ esrc, float* __restrict__ edst, int N, int E)
{
  int t = threadIdx.x;
  for (long e = (long)blockIdx.x*256 + t; e < E; e += (long)gridDim.x*256)
    atomicAdd(deg + dst[e], 1);

  int lane = t & 63, wv = t >> 6;
  int r16 = lane & 15, g = lane >> 4;
  int n0 = blockIdx.x * 32;
  int ntS = (wv*17) >> 2, ntE = ((wv+1)*17) >> 2;

  #pragma unroll
  for (int mt = 0; mt < 2; ++mt) {
    int arow = n0 + mt*16 + r16; if (arow >= N) arow = N-1;
    bf16x8 a[4];
    #pragma unroll
    for (int kc = 0; kc < 4; ++kc) {
      const float* ap = X + (long)arow*DINC + kc*32 + g*8;
      f32x4 x0 = *(const f32x4*)ap;
      f32x4 x1 = *(const f32x4*)(ap + 4);
      bf16x8 af;
      af[0]=f2bf(x0[0]); af[1]=f2bf(x0[1]); af[2]=f2bf(x0[2]); af[3]=f2bf(x0[3]);
      af[4]=f2bf(x1[0]); af[5]=f2bf(x1[1]); af[6]=f2bf(x1[2]); af[7]=f2bf(x1[3]);
      a[kc] = af;
    }
    for (int nt = ntS; nt < ntE; ++nt) {
      f32x4 acc = (f32x4){0,0,0,0};
      #pragma unroll
      for (int kc = 0; kc < 4; ++kc) {
        bf16x8 bf = *(const bf16x8*)(wcmb + (nt*16 + r16)*DINC + kc*32 + g*8);
        acc = __builtin_amdgcn_mfma_f32_16x16x32_bf16(a[kc], bf, acc, 0, 0, 0);
      }
      int j = nt*16 + r16;   // D: col = lane&15, row = g*4 + r
      #pragma unroll
      for (int r = 0; r < 4; ++r) {
        int n = n0 + mt*16 + g*4 + r;
        if (n >= N) continue;
        float v = acc[r];
        if      (j < 128) hsrcbf[(long)n*OUTC + j] = f2bf(v);
        else if (j < 256) hdstbf[(long)n*OUTC + (j-128)] = f2bf(v);
        else if (j < 260) esrc[(long)n*HH + (j-256)] = v;
        else if (j < 264) edst[(long)n*HH + (j-260)] = v;
      }
    }
  }
}

// ---------------- scan: 3-phase parallel exclusive scan of deg ----------------
__global__ __launch_bounds__(256) void scan1(const int* __restrict__ deg, int* __restrict__ bsum, int N)
{
  __shared__ int sh[256];
  int t = threadIdx.x, blk = blockIdx.x;
  int R = (N + SCAN_B*256 - 1) / (SCAN_B*256);
  int base = (blk*256 + t)*R;
  int s = 0;
  for (int i = 0; i < R; ++i) { int idx = base + i; if (idx < N) s += deg[idx]; }
  sh[t] = s; __syncthreads();
  for (int d = 128; d > 0; d >>= 1) { if (t < d) sh[t] += sh[t+d]; __syncthreads(); }
  if (t == 0) bsum[blk] = sh[0];
}

__global__ __launch_bounds__(64) void scan2(const int* __restrict__ bsum, int* __restrict__ bpre,
                                            int* __restrict__ off, int N)
{
  if (threadIdx.x == 0) {
    int r = 0;
    for (int b = 0; b < SCAN_B; ++b) { bpre[b] = r; r += bsum[b]; }
    off[N] = r;
  }
}

__global__ __launch_bounds__(256) void scan3(const int* __restrict__ deg, const int* __restrict__ bpre,
                                             int* __restrict__ off, int* __restrict__ cursor, int N)
{
  __shared__ int sh[256];
  int t = threadIdx.x, blk = blockIdx.x;
  int R = (N + SCAN_B*256 - 1) / (SCAN_B*256);
  int base = (blk*256 + t)*R;
  int s = 0;
  for (int i = 0; i < R; ++i) { int idx = base + i; if (idx < N) s += deg[idx]; }
  sh[t] = s; __syncthreads();
  for (int d = 1; d < 256; d <<= 1) {
    int v = (t >= d) ? sh[t-d] : 0;
    __syncthreads();
    sh[t] += v;
    __syncthreads();
  }
  int r = bpre[blk] + sh[t] - s;
  for (int i = 0; i < R; ++i) {
    int idx = base + i;
    if (idx < N) { off[idx] = r; cursor[idx] = r; r += deg[idx]; }
  }
}

// ---------------- scatter: 8B CSR records {src, eid} ----------------
__global__ __launch_bounds__(256) void scatter_kernel(
    const int* __restrict__ src, const int* __restrict__ dst,
    int* __restrict__ cursor, unsigned long long* __restrict__ csr, int E)
{
  int e = blockIdx.x*256 + threadIdx.x;
  if (e >= E) return;
  int p = atomicAdd(cursor + dst[e], 1);
  csr[p] = ((unsigned long long)(unsigned)src[e] << 32) | (unsigned)e;
}

// ---------------- K4: FUSED per-node aggregation — prefetched gathers, unrolled Phase B ----------------
// Wave = node (R9 skeleton: non-persistent, fences per chunk). Per 16-edge chunk:
//   csr load -> shfl src ids -> ISSUE all 16 hsrc row-gathers + 16 esrc loads (regs)
//   Xe gather -> A-frags -> LDS + logit MFMA -> nu2 (their latency covers the prefetches)
//   n1[16] from prefetched esrc; Phase B = fully-unrolled 16-step FMA loop, no loads.
__global__ __launch_bounds__(256) void aggregate_fused(
    const float* __restrict__ Xe, const unsigned short* __restrict__ veb,
    const unsigned* __restrict__ hsrcbfu, const unsigned* __restrict__ hdstbfu,
    const float* __restrict__ esrc, const float* __restrict__ edst,
    const unsigned long long* __restrict__ csr, const int* __restrict__ off,
    const unsigned short* __restrict__ webf, float* __restrict__ out, int N)
{
  struct WaveLds {
    union {
      unsigned short XeL[16][DINC+8];   // bf16 Xe rows of current chunk
      float Ylds[HH][DINC+4];           // epilogue Y (reuses dead XeL)
    };
    float S2[16][HH];                   // nu2 per (edge-in-chunk, head)
  };
  __shared__ WaveLds L[4];

  int t = threadIdx.x, wid = t >> 6, lane = t & 63;
  int r16 = lane & 15, g = lane >> 4;
  int hl = g;                  // head owned by this lane (cols 2*lane)
  int j0 = 2*lane;
  int n = blockIdx.x*4 + wid;
  bool valid = (n < N);
  int beg = 0, end = 0;
  if (valid) { beg = off[n]; end = off[n+1]; }

  bf16x8 vebf[4];
  #pragma unroll
  for (int kc = 0; kc < 4; ++kc)
    vebf[kc] = *(const bf16x8*)(veb + r16*DINC + kc*32 + g*8);

  unsigned bu = valid ? hdstbfu[(long)n*64 + lane] : 0;
  f32x4 edh4 = valid ? *(const f32x4*)(edst + (long)n*HH) : (f32x4){0,0,0,0};
  float edh  = edh4[hl];
  float edhr = edh4[r16 & 3];

  f32x2 acc = {0.f,0.f};
  f32x2 Y0={0,0}, Y1={0,0}, Y2={0,0}, Y3={0,0};
  float s1h = 0.f;
  f32x4 s2v = {0,0,0,0};

  for (int p0 = beg; p0 < end; p0 += 16) {
    // --- csr entry for edge r16 (redundant across g groups) ---
    long pr = (long)p0 + r16; if (pr >= end) pr = end - 1;
    unsigned long long pk = csr[pr];
    int s_ = (int)(pk >> 32);
    long eid = (long)(unsigned)pk;

    // --- prefetch: hsrc rows + esrc scalars for ALL 16 edges (issued before Xe loads) ---
    unsigned hu[16];
    float esv[16];
    #pragma unroll
    for (int i = 0; i < 16; ++i) {
      int si = __shfl(s_, i, 64);
      hu[i]  = hsrcbfu[(long)si*64 + lane];
      esv[i] = esrc[(long)si*HH + hl];
    }

    // --- Phase A: Xe gather -> A-frags -> LDS + MFMA logits ---
    f32x4 accq = (f32x4){0,0,0,0};
    #pragma unroll
    for (int kc = 0; kc < 4; ++kc) {
      const float* ap = Xe + eid*DINC + kc*32 + g*8;
      f32x4 x0 = *(const f32x4*)ap;
      f32x4 x1 = *(const f32x4*)(ap + 4);
      bf16x8 af;
      af[0]=f2bf(x0[0]); af[1]=f2bf(x0[1]); af[2]=f2bf(x0[2]); af[3]=f2bf(x0[3]);
      af[4]=f2bf(x1[0]); af[5]=f2bf(x1[1]); af[6]=f2bf(x1[2]); af[7]=f2bf(x1[3]);
      *(bf16x8*)&L[wid].XeL[r16][kc*32 + g*8] = af;
      accq = __builtin_amdgcn_mfma_f32_16x16x32_bf16(af, vebf[kc], accq, 0, 0, 0);
    }
    if (r16 < HH) {            // logits D: col r16 = head, row g*4+r = edge-in-chunk
      #pragma unroll
      for (int r = 0; r < 4; ++r) {
        float n2 = ((p0 + g*4 + r) < end) ? __expf(leaky(accq[r] + edhr)) : 0.f;
        L[wid].S2[g*4 + r][r16] = n2;
      }
    }
    asm volatile("s_waitcnt lgkmcnt(0)" ::: "memory");
    __builtin_amdgcn_sched_barrier(0);

    // --- n1 per edge from prefetched esrc (masked tail) ---
    float n1v[16];
    #pragma unroll
    for (int i = 0; i < 16; ++i) {
      float n1 = ((p0 + i) < end) ? __expf(leaky(esv[i] + edh)) : 0.f;
      n1v[i] = n1;
      s1h += n1;
    }

    // --- Phase B: fully unrolled, zero loads (LDS nu2/xe + reg hu/n1) ---
    #pragma unroll
    for (int i = 0; i < 16; ++i) {
      f32x4 nu2 = *(const f32x4*)L[wid].S2[i];
      unsigned xu = *(const unsigned*)&L[wid].XeL[i][j0];
      f32x2 xe; xe[0] = bf2f(xu & 0xffffu); xe[1] = bf2f(xu >> 16);
      f32x2 hs; hs[0] = bf2f(hu[i] & 0xffffu); hs[1] = bf2f(hu[i] >> 16);
      s2v += nu2;
      acc += n1v[i]*hs;
      Y0 += nu2[0]*xe; Y1 += nu2[1]*xe; Y2 += nu2[2]*xe; Y3 += nu2[3]*xe;
    }
    asm volatile("" ::: "memory");
  }

  float is1h = (s1h != 0.f) ? 1.f / s1h : 0.f;
  f32x4 is2;
  #pragma unroll
  for (int h=0; h<HH; ++h) is2[h] = (s2v[h] != 0.f) ? 1.f / s2v[h] : 0.f;
  acc *= is1h;
  Y0 *= is2[0]; Y1 *= is2[1]; Y2 *= is2[2]; Y3 *= is2[3];

  // Y -> LDS (overlays dead XeL; in-order DS per wave makes this safe)
  *(f32x2*)&L[wid].Ylds[0][j0] = Y0;
  *(f32x2*)&L[wid].Ylds[1][j0] = Y1;
  *(f32x2*)&L[wid].Ylds[2][j0] = Y2;
  *(f32x2*)&L[wid].Ylds[3][j0] = Y3;
  asm volatile("s_waitcnt lgkmcnt(0)" ::: "memory");
  __builtin_amdgcn_sched_barrier(0);

  // finish: out[n,j] = h_dst + acc + sum_k Y[hl][k]*We[j,k]  (webf[k][j] bf16, L1-resident)
  const float* yp = L[wid].Ylds[hl];
  float f0 = 0.f, f1 = 0.f;
  #pragma unroll 8
  for (int k = 0; k < DINC; ++k) {
    unsigned wu = *(const unsigned*)(webf + k*OUTC + j0);
    float y = yp[k];
    f0 += y * bf2f(wu & 0xffffu);
    f1 += y * bf2f(wu >> 16);
  }
  if (valid) {
    out[(long)n*OUTC + j0]     = bf2f(bu & 0xffffu) + acc[0] + f0;
    out[(long)n*OUTC + j0 + 1] = bf2f(bu >> 16)     + acc[1] + f1;
  }
}

extern "C" void kernel_launch(void* const* d_in, const int* in_sizes, int n_in,
                              void* d_out, int out_size, void* d_ws, size_t ws_size,
                              hipStream_t stream) {
  const float* X   = (const float*)d_in[0];
  const float* Xe  = (const float*)d_in[1];
  const float* Ws  = (const float*)d_in[2];
  const float* Wd  = (const float*)d_in[3];
  const float* We  = (const float*)d_in[4];
  const float* as_ = (const float*)d_in[5];
  const float* ad_ = (const float*)d_in[6];
  const float* ae_ = (const float*)d_in[7];
  const int* src   = (const int*)d_in[8];
  const int* dst   = (const int*)d_in[9];
  int N = in_sizes[0] / DINC;
  int E = in_sizes[8];
  float* out = (float*)d_out;

  char* ws = (char*)d_ws;
  auto align256 = [](size_t x){ return (x + 255) & ~(size_t)255; };
  size_t o_hsrc  = 0;                                        // bf16 [N][128]
  size_t o_hdst  = align256(o_hsrc + (size_t)N*OUTC*2);      // bf16 [N][128]
  size_t o_esrc  = align256(o_hdst + (size_t)N*OUTC*2);
  size_t o_edst  = align256(o_esrc + (size_t)N*HH*4);
  size_t o_csr   = align256(o_edst + (size_t)N*HH*4);        // u64 [E], CSR order
  size_t o_wcmb  = align256(o_csr  + (size_t)E*8);
  size_t o_webf  = align256(o_wcmb + (size_t)NCMB*DINC*2);
  size_t o_veb   = align256(o_webf + (size_t)DINC*OUTC*2);
  size_t o_deg   = align256(o_veb  + (size_t)16*DINC*2);
  size_t o_off   = align256(o_deg  + (size_t)N*4);
  size_t o_cur   = align256(o_off  + (size_t)(N+4)*4);
  size_t o_bsum  = align256(o_cur  + (size_t)N*4);
  size_t o_bpre  = align256(o_bsum + (size_t)SCAN_B*4);

  unsigned short* hsrcbf = (unsigned short*)(ws + o_hsrc);
  unsigned short* hdstbf = (unsigned short*)(ws + o_hdst);
  float* esrc  = (float*)(ws + o_esrc);
  float* edstp = (float*)(ws + o_edst);
  unsigned long long* csr = (unsigned long long*)(ws + o_csr);
  unsigned short* wcmb = (unsigned short*)(ws + o_wcmb);
  unsigned short* webf = (unsigned short*)(ws + o_webf);
  unsigned short* veb  = (unsigned short*)(ws + o_veb);
  int* deg     = (int*)(ws + o_deg);
  int* off     = (int*)(ws + o_off);
  int* cursor  = (int*)(ws + o_cur);
  int* bsum    = (int*)(ws + o_bsum);
  int* bpre    = (int*)(ws + o_bpre);

  prep_kernel<<<32, 256, 0, stream>>>(Ws, Wd, We, as_, ad_, ae_, wcmb, webf, veb, deg, N);
  node_mfma<<<(N + 31)/32, 256, 0, stream>>>(X, wcmb, dst, deg, hsrcbf, hdstbf, esrc, edstp, N, E);
  scan1<<<SCAN_B, 256, 0, stream>>>(deg, bsum, N);
  scan2<<<1, 64, 0, stream>>>(bsum, bpre, off, N);
  scan3<<<SCAN_B, 256, 0, stream>>>(deg, bpre, off, cursor, N);
  scatter_kernel<<<(E + 255)/256, 256, 0, stream>>>(src, dst, cursor, csr, E);
  aggregate_fused<<<(N + 3)/4, 256, 0, stream>>>(Xe, veb, (const unsigned*)hsrcbf, (const unsigned*)hdstbf,
                                                 esrc, edstp, csr, off, webf, out, N);
}

// Round 14
// 364.989 us; speedup vs baseline: 1.4415x; 1.1323x over previous
//
#include <hip/hip_runtime.h>

constexpr int HH   = 4;    // heads
constexpr int DINC = 128;  // input feature dim
constexpr int OUTC = 128;  // output feature dim (H*D)
constexpr int NCMB = 272;  // combined B cols: 128 Ws | 128 Wd | 4 vs | 4 vd | 8 pad
constexpr int SCAN_B = 64;

typedef __attribute__((ext_vector_type(4))) float f32x4;
typedef __attribute__((ext_vector_type(2))) float f32x2;
typedef __attribute__((ext_vector_type(8))) short bf16x8;

__device__ __forceinline__ float leaky(float x){ return x >= 0.f ? x : 0.2f*x; }
__device__ __forceinline__ unsigned short f2bf(float f){ unsigned u=__float_as_uint(f); return (unsigned short)((u + 0x7FFFu + ((u>>16)&1u))>>16); }
__device__ __forceinline__ float bf2f(unsigned s){ return __uint_as_float(s<<16); }

// ---------------- K0: prep — element-parallel (+ deg zeroing) ----------------
__global__ __launch_bounds__(256) void prep_kernel(
    const float* __restrict__ Ws, const float* __restrict__ Wd, const float* __restrict__ We,
    const float* __restrict__ as_, const float* __restrict__ ad_, const float* __restrict__ ae_,
    unsigned short* __restrict__ wcmb, unsigned short* __restrict__ webf,
    unsigned short* __restrict__ veb, int* __restrict__ deg, int N)
{
  int tid = blockIdx.x*256 + threadIdx.x;
  int stride = gridDim.x*256;
  for (int idx = tid; idx < NCMB*DINC; idx += stride) {
    int j = idx >> 7, k = idx & 127;
    float w;
    if      (j < 128) w = Ws[j*DINC + k];
    else if (j < 256) w = Wd[(j-128)*DINC + k];
    else if (j < 260) { int h=j-256; float s=0.f; for(int d=0;d<32;++d) s += as_[h*32+d]*Ws[(h*32+d)*DINC+k]; w=s; }
    else if (j < 264) { int h=j-260; float s=0.f; for(int d=0;d<32;++d) s += ad_[h*32+d]*Wd[(h*32+d)*DINC+k]; w=s; }
    else w = 0.f;
    wcmb[idx] = f2bf(w);
  }
  for (int idx = tid; idx < 16*DINC; idx += stride) {   // veb[16][128]: 4 real head rows
    int h = idx >> 7, k = idx & 127;
    float w = 0.f;
    if (h < HH) { float s=0.f; for(int d=0;d<32;++d) s += ae_[h*32+d]*We[(h*32+d)*DINC+k]; w=s; }
    veb[idx] = f2bf(w);
  }
  for (int idx = tid; idx < DINC*OUTC; idx += stride) { // webf[k][j] = We[j][k]
    int k = idx >> 7, j = idx & 127;
    webf[idx] = f2bf(We[j*DINC + k]);
  }
  for (int idx = tid; idx < N; idx += stride) deg[idx] = 0;
}

// ---------------- K1: MFMA node GEMM C[32,272] = X @ [Ws|Wd|vs|vd]^T + fused histogram ----------------
__global__ __launch_bounds__(256) void node_mfma(
    const float* __restrict__ X, const unsigned short* __restrict__ wcmb,
    const int* __restrict__ dst, int* __restrict__ deg,
    unsigned short* __restrict__ hsrcbf, unsigned short* __restrict__ hdstbf,
    float* __restrict__ esrc, float* __restrict__ edst, int N, int E)
{
  int t = threadIdx.x;
  for (long e = (long)blockIdx.x*256 + t; e < E; e += (long)gridDim.x*256)
    atomicAdd(deg + dst[e], 1);

  int lane = t & 63, wv = t >> 6;
  int r16 = lane & 15, g = lane >> 4;
  int n0 = blockIdx.x * 32;
  int ntS = (wv*17) >> 2, ntE = ((wv+1)*17) >> 2;

  #pragma unroll
  for (int mt = 0; mt < 2; ++mt) {
    int arow = n0 + mt*16 + r16; if (arow >= N) arow = N-1;
    bf16x8 a[4];
    #pragma unroll
    for (int kc = 0; kc < 4; ++kc) {
      const float* ap = X + (long)arow*DINC + kc*32 + g*8;
      f32x4 x0 = *(const f32x4*)ap;
      f32x4 x1 = *(const f32x4*)(ap + 4);
      bf16x8 af;
      af[0]=f2bf(x0[0]); af[1]=f2bf(x0[1]); af[2]=f2bf(x0[2]); af[3]=f2bf(x0[3]);
      af[4]=f2bf(x1[0]); af[5]=f2bf(x1[1]); af[6]=f2bf(x1[2]); af[7]=f2bf(x1[3]);
      a[kc] = af;
    }
    for (int nt = ntS; nt < ntE; ++nt) {
      f32x4 acc = (f32x4){0,0,0,0};
      #pragma unroll
      for (int kc = 0; kc < 4; ++kc) {
        bf16x8 bf = *(const bf16x8*)(wcmb + (nt*16 + r16)*DINC + kc*32 + g*8);
        acc = __builtin_amdgcn_mfma_f32_16x16x32_bf16(a[kc], bf, acc, 0, 0, 0);
      }
      int j = nt*16 + r16;   // D: col = lane&15, row = g*4 + r
      #pragma unroll
      for (int r = 0; r < 4; ++r) {
        int n = n0 + mt*16 + g*4 + r;
        if (n >= N) continue;
        float v = acc[r];
        if      (j < 128) hsrcbf[(long)n*OUTC + j] = f2bf(v);
        else if (j < 256) hdstbf[(long)n*OUTC + (j-128)] = f2bf(v);
        else if (j < 260) esrc[(long)n*HH + (j-256)] = v;
        else if (j < 264) edst[(long)n*HH + (j-260)] = v;
      }
    }
  }
}

// ---------------- scan: 3-phase parallel exclusive scan of deg ----------------
__global__ __launch_bounds__(256) void scan1(const int* __restrict__ deg, int* __restrict__ bsum, int N)
{
  __shared__ int sh[256];
  int t = threadIdx.x, blk = blockIdx.x;
  int R = (N + SCAN_B*256 - 1) / (SCAN_B*256);
  int base = (blk*256 + t)*R;
  int s = 0;
  for (int i = 0; i < R; ++i) { int idx = base + i; if (idx < N) s += deg[idx]; }
  sh[t] = s; __syncthreads();
  for (int d = 128; d > 0; d >>= 1) { if (t < d) sh[t] += sh[t+d]; __syncthreads(); }
  if (t == 0) bsum[blk] = sh[0];
}

__global__ __launch_bounds__(64) void scan2(const int* __restrict__ bsum, int* __restrict__ bpre,
                                            int* __restrict__ off, int N)
{
  if (threadIdx.x == 0) {
    int r = 0;
    for (int b = 0; b < SCAN_B; ++b) { bpre[b] = r; r += bsum[b]; }
    off[N] = r;
  }
}

__global__ __launch_bounds__(256) void scan3(const int* __restrict__ deg, const int* __restrict__ bpre,
                                             int* __restrict__ off, int* __restrict__ cursor, int N)
{
  __shared__ int sh[256];
  int t = threadIdx.x, blk = blockIdx.x;
  int R = (N + SCAN_B*256 - 1) / (SCAN_B*256);
  int base = (blk*256 + t)*R;
  int s = 0;
  for (int i = 0; i < R; ++i) { int idx = base + i; if (idx < N) s += deg[idx]; }
  sh[t] = s; __syncthreads();
  for (int d = 1; d < 256; d <<= 1) {
    int v = (t >= d) ? sh[t-d] : 0;
    __syncthreads();
    sh[t] += v;
    __syncthreads();
  }
  int r = bpre[blk] + sh[t] - s;
  for (int i = 0; i < R; ++i) {
    int idx = base + i;
    if (idx < N) { off[idx] = r; cursor[idx] = r; r += deg[idx]; }
  }
}

// ---------------- scatter: 8B CSR records {src, eid} ----------------
__global__ __launch_bounds__(256) void scatter_kernel(
    const int* __restrict__ src, const int* __restrict__ dst,
    int* __restrict__ cursor, unsigned long long* __restrict__ csr, int E)
{
  int e = blockIdx.x*256 + threadIdx.x;
  if (e >= E) return;
  int p = atomicAdd(cursor + dst[e], 1);
  csr[p] = ((unsigned long long)(unsigned)src[e] << 32) | (unsigned)e;
}

// ---------------- K4: FUSED per-node aggregation — R9 verbatim + LDS union (ONLY change) ----------------
// Wave = node. Per 16-edge chunk: Phase A gathers Xe rows as MFMA A-frags -> LDS + logit
// MFMA + nu2 -> LDS; Phase B streams the chunk from LDS (hsrc/esrc gathers in-loop, as R9).
// LDS union: Ylds overlays dead XeL (R12-validated safe) -> 18.8 KB -> 8 blocks/CU.
__global__ __launch_bounds__(256) void aggregate_fused(
    const float* __restrict__ Xe, const unsigned short* __restrict__ veb,
    const unsigned* __restrict__ hsrcbfu, const unsigned* __restrict__ hdstbfu,
    const float* __restrict__ esrc, const float* __restrict__ edst,
    const unsigned long long* __restrict__ csr, const int* __restrict__ off,
    const unsigned short* __restrict__ webf, float* __restrict__ out, int N)
{
  struct WaveLds {
    union {
      unsigned short XeL[16][DINC+8];   // bf16 Xe rows of current chunk (pad 8)
      float Ylds[HH][DINC+4];           // epilogue Y (reuses dead XeL)
    };
    float S2[16][HH];                   // nu2 per (edge-in-chunk, head)
    int srcL[16];
  };
  __shared__ WaveLds L[4];

  int t = threadIdx.x, wid = t >> 6, lane = t & 63;
  int r16 = lane & 15, g = lane >> 4;
  int n = blockIdx.x*4 + wid;
  bool valid = (n < N);
  int beg = 0, end = 0;
  if (valid) { beg = off[n]; end = off[n+1]; }
  int hl = g;                  // head owned by this lane (cols 2*lane)
  int j0 = 2*lane;
  f32x4 edh4 = valid ? *(const f32x4*)(edst + (long)n*HH) : (f32x4){0,0,0,0};
  float edh  = edh4[hl];
  float edhr = edh4[r16 & 3];

  bf16x8 vebf[4];
  #pragma unroll
  for (int kc = 0; kc < 4; ++kc)
    vebf[kc] = *(const bf16x8*)(veb + r16*DINC + kc*32 + g*8);

  f32x2 acc = {0.f,0.f};
  f32x2 Y0={0,0}, Y1={0,0}, Y2={0,0}, Y3={0,0};
  float s1h = 0.f;
  f32x4 s2v = {0,0,0,0};

  for (int p0 = beg; p0 < end; p0 += 16) {
    int cnt = min(16, end - p0);
    // --- Phase A: csr entries, Xe row gather -> A-frags -> LDS + MFMA logits ---
    long pr = (long)p0 + r16; if (pr >= end) pr = end - 1;
    unsigned long long pk = csr[pr];
    long eid = (long)(unsigned)pk;
    if (lane < 16) L[wid].srcL[lane] = (int)(pk >> 32);

    f32x4 accq = (f32x4){0,0,0,0};
    #pragma unroll
    for (int kc = 0; kc < 4; ++kc) {
      const float* ap = Xe + eid*DINC + kc*32 + g*8;
      f32x4 x0 = *(const f32x4*)ap;
      f32x4 x1 = *(const f32x4*)(ap + 4);
      bf16x8 af;
      af[0]=f2bf(x0[0]); af[1]=f2bf(x0[1]); af[2]=f2bf(x0[2]); af[3]=f2bf(x0[3]);
      af[4]=f2bf(x1[0]); af[5]=f2bf(x1[1]); af[6]=f2bf(x1[2]); af[7]=f2bf(x1[3]);
      *(bf16x8*)&L[wid].XeL[r16][kc*32 + g*8] = af;
      accq = __builtin_amdgcn_mfma_f32_16x16x32_bf16(af, vebf[kc], accq, 0, 0, 0);
    }
    if (r16 < HH) {            // logits D: col r16 = head, row g*4+r = edge-in-chunk
      #pragma unroll
      for (int r = 0; r < 4; ++r) {
        float n2 = ((p0 + g*4 + r) < end) ? __expf(leaky(accq[r] + edhr)) : 0.f;
        L[wid].S2[g*4 + r][r16] = n2;
      }
    }
    asm volatile("s_waitcnt lgkmcnt(0)" ::: "memory");   // wave-local: drain LDS writes
    __builtin_amdgcn_sched_barrier(0);

    // --- Phase B: stream the chunk's edges from LDS ---
    for (int i = 0; i < cnt; ++i) {
      int s_ = L[wid].srcL[i];
      f32x4 nu2 = *(const f32x4*)L[wid].S2[i];
      unsigned xu = *(const unsigned*)&L[wid].XeL[i][j0];
      unsigned hu = hsrcbfu[(long)s_*64 + lane];
      float es_ = esrc[(long)s_*HH + hl];
      float n1 = __expf(leaky(es_ + edh));
      f32x2 xe; xe[0] = bf2f(xu & 0xffffu); xe[1] = bf2f(xu >> 16);
      f32x2 hs; hs[0] = bf2f(hu & 0xffffu); hs[1] = bf2f(hu >> 16);
      s1h += n1; s2v += nu2;
      acc += n1*hs;
      Y0 += nu2[0]*xe; Y1 += nu2[1]*xe; Y2 += nu2[2]*xe; Y3 += nu2[3]*xe;
    }
    asm volatile("" ::: "memory");   // keep next chunk's LDS writes after these reads
  }

  float is1h = (s1h != 0.f) ? 1.f / s1h : 0.f;
  f32x4 is2;
  #pragma unroll
  for (int h=0; h<HH; ++h) is2[h] = (s2v[h] != 0.f) ? 1.f / s2v[h] : 0.f;
  acc *= is1h;
  Y0 *= is2[0]; Y1 *= is2[1]; Y2 *= is2[2]; Y3 *= is2[3];

  // Y -> LDS (overlays dead XeL; wave-local in-order DS + fence make this safe)
  asm volatile("s_waitcnt lgkmcnt(0)" ::: "memory");
  __builtin_amdgcn_sched_barrier(0);
  *(f32x2*)&L[wid].Ylds[0][j0] = Y0;
  *(f32x2*)&L[wid].Ylds[1][j0] = Y1;
  *(f32x2*)&L[wid].Ylds[2][j0] = Y2;
  *(f32x2*)&L[wid].Ylds[3][j0] = Y3;
  asm volatile("s_waitcnt lgkmcnt(0)" ::: "memory");
  __builtin_amdgcn_sched_barrier(0);

  // finish: out[n,j] = h_dst + acc + sum_k Y[hl][k]*We[j,k]  (webf[k][j] bf16, L1-resident)
  const float* yp = L[wid].Ylds[hl];
  float f0 = 0.f, f1 = 0.f;
  #pragma unroll 8
  for (int k = 0; k < DINC; ++k) {
    unsigned wu = *(const unsigned*)(webf + k*OUTC + j0);
    float y = yp[k];
    f0 += y * bf2f(wu & 0xffffu);
    f1 += y * bf2f(wu >> 16);
  }
  if (valid) {
    unsigned bu = hdstbfu[(long)n*64 + lane];
    out[(long)n*OUTC + j0]     = bf2f(bu & 0xffffu) + acc[0] + f0;
    out[(long)n*OUTC + j0 + 1] = bf2f(bu >> 16)     + acc[1] + f1;
  }
}

extern "C" void kernel_launch(void* const* d_in, const int* in_sizes, int n_in,
                              void* d_out, int out_size, void* d_ws, size_t ws_size,
                              hipStream_t stream) {
  const float* X   = (const float*)d_in[0];
  const float* Xe  = (const float*)d_in[1];
  const float* Ws  = (const float*)d_in[2];
  const float* Wd  = (const float*)d_in[3];
  const float* We  = (const float*)d_in[4];
  const float* as_ = (const float*)d_in[5];
  const float* ad_ = (const float*)d_in[6];
  const float* ae_ = (const float*)d_in[7];
  const int* src   = (const int*)d_in[8];
  const int* dst   = (const int*)d_in[9];
  int N = in_sizes[0] / DINC;
  int E = in_sizes[8];
  float* out = (float*)d_out;

  char* ws = (char*)d_ws;
  auto align256 = [](size_t x){ return (x + 255) & ~(size_t)255; };
  size_t o_hsrc  = 0;                                        // bf16 [N][128]
  size_t o_hdst  = align256(o_hsrc + (size_t)N*OUTC*2);      // bf16 [N][128]
  size_t o_esrc  = align256(o_hdst + (size_t)N*OUTC*2);
  size_t o_edst  = align256(o_esrc + (size_t)N*HH*4);
  size_t o_csr   = align256(o_edst + (size_t)N*HH*4);        // u64 [E], CSR order
  size_t o_wcmb  = align256(o_csr  + (size_t)E*8);
  size_t o_webf  = align256(o_wcmb + (size_t)NCMB*DINC*2);
  size_t o_veb   = align256(o_webf + (size_t)DINC*OUTC*2);
  size_t o_deg   = align256(o_veb  + (size_t)16*DINC*2);
  size_t o_off   = align256(o_deg  + (size_t)N*4);
  size_t o_cur   = align256(o_off  + (size_t)(N+4)*4);
  size_t o_bsum  = align256(o_cur  + (size_t)N*4);
  size_t o_bpre  = align256(o_bsum + (size_t)SCAN_B*4);

  unsigned short* hsrcbf = (unsigned short*)(ws + o_hsrc);
  unsigned short* hdstbf = (unsigned short*)(ws + o_hdst);
  float* esrc  = (float*)(ws + o_esrc);
  float* edstp = (float*)(ws + o_edst);
  unsigned long long* csr = (unsigned long long*)(ws + o_csr);
  unsigned short* wcmb = (unsigned short*)(ws + o_wcmb);
  unsigned short* webf = (unsigned short*)(ws + o_webf);
  unsigned short* veb  = (unsigned short*)(ws + o_veb);
  int* deg     = (int*)(ws + o_deg);
  int* off     = (int*)(ws + o_off);
  int* cursor  = (int*)(ws + o_cur);
  int* bsum    = (int*)(ws + o_bsum);
  int* bpre    = (int*)(ws + o_bpre);

  prep_kernel<<<32, 256, 0, stream>>>(Ws, Wd, We, as_, ad_, ae_, wcmb, webf, veb, deg, N);
  node_mfma<<<(N + 31)/32, 256, 0, stream>>>(X, wcmb, dst, deg, hsrcbf, hdstbf, esrc, edstp, N, E);
  scan1<<<SCAN_B, 256, 0, stream>>>(deg, bsum, N);
  scan2<<<1, 64, 0, stream>>>(bsum, bpre, off, N);
  scan3<<<SCAN_B, 256, 0, stream>>>(deg, bpre, off, cursor, N);
  scatter_kernel<<<(E + 255)/256, 256, 0, stream>>>(src, dst, cursor, csr, E);
  aggregate_fused<<<(N + 3)/4, 256, 0, stream>>>(Xe, veb, (const unsigned*)hsrcbf, (const unsigned*)hdstbf,
                                                 esrc, edstp, csr, off, webf, out, N);
}